// Round 1
// 230.848 us; speedup vs baseline: 1.0227x; 1.0227x over previous
//
#include <hip/hip_runtime.h>
#include <math.h>

#define RBINS 160
#define BROWS 65536
#define ROWELEMS 480                    // 160 bins * 3 channels
#define ROWF4 (ROWELEMS / 4)            // 120
#define TASKS_PER_ROW 40                // each task: 4 bins x 3 ch = 12 elements
#define NTHREADS 256
#define TOTAL_TASKS (BROWS * TASKS_PER_ROW)   // 2,621,440
#define NBLOCKS (TOTAL_TASKS / NTHREADS)      // 10240

__device__ __forceinline__ float clamp01(float x) {
    return __builtin_amdgcn_fmed3f(x, 0.0f, 1.0f);
}

// Stencil over a 24-float register window. P = (wave-uniform) misalignment 0..3,
// so all w[] indices are compile-time constants (stay in VGPRs, rule #20).
// Tap u-index for output m, tap t (1..4): P + m + 3*(t-1); max = P+11+9 <= 23.
template<int P>
__device__ __forceinline__ void stencil_store(
    const float* __restrict__ w,
    float u1, float u2, float u3, float u4,
    float4* __restrict__ dst, bool dofade, int j0)
{
    float r[12];
    #pragma unroll
    for (int m = 0; m < 12; ++m) {
        float acc = u1 * w[P + m];
        acc = fmaf(u2, w[P + m + 3], acc);
        acc = fmaf(u3, w[P + m + 6], acc);
        acc = fmaf(u4, w[P + m + 9], acc);
        r[m] = acc;
    }
    if (dofade) {
        #pragma unroll
        for (int mb = 0; mb < 4; ++mb) {
            const int j = j0 + mb;
            const float t = (float)(RBINS - 1 - j) * 0.125f;
            const float ff = (j >= RBINS - 8) ? t * t : 1.0f;
            r[3*mb+0] *= ff; r[3*mb+1] *= ff; r[3*mb+2] *= ff;
        }
    }
    dst[0] = make_float4(r[0], r[1], r[2],  r[3]);
    dst[1] = make_float4(r[4], r[5], r[6],  r[7]);
    dst[2] = make_float4(r[8], r[9], r[10], r[11]);
}

__global__ __launch_bounds__(NTHREADS, 6) void beat_kernel(
    const float* __restrict__ hist,
    const float* __restrict__ color,
    const float* __restrict__ p_offset,
    const float* __restrict__ p_persist,
    const float* __restrict__ p_diff,
    const float* __restrict__ p_dt,
    const float* __restrict__ p_amount,
    const float* __restrict__ p_spread,
    float* __restrict__ out)
{
    const int task = blockIdx.x * NTHREADS + threadIdx.x;
    const int b = task / TASKS_PER_ROW;           // row
    const int c = task - b * TASKS_PER_ROW;       // 4-bin column task within row

    // ---- uniform scalar parameters (compile to s_load + SALU/VALU once) ----
    const float offs = *p_offset;
    const float pers = *p_persist;
    const float diff = *p_diff;
    const float dts  = *p_dt;

    const float dt       = fminf(fmaxf(dts, 0.0f), 0.05f);
    const float dt_scale = dt * 60.0f;
    const float s        = offs * dt_scale;
    const float dt_pers  = __powf(pers, dt_scale);
    const int   dfl      = (int)floorf(s);
    const float frac     = s - (float)dfl;        // uniform: floor(i+s)=i+dfl in interior
    const float kk = 0.15f * diff;
    const float cc = 1.0f - 2.0f * kk;
    const float wl = (1.0f - frac) * dt_pers;
    const float wr = frac * dt_pers;
    // interior 4-tap coefficients (taps t=1..4 of the old 6-tap table; t=0,5 are 0)
    const float u1 = wr * kk;
    const float u2 = fmaf(wl, kk, wr * cc);
    const float u3 = fmaf(wl, cc, wr * kk);
    const float u4 = wl * kk;

    // valid source-bin range: 0<=i<=R-1 AND 0 <= i+s < R-1, as element range
    const int ilo = max(0, (int)ceilf(-s));
    const int ihi = min(RBINS - 1, (int)ceilf((float)(RBINS - 1) - s) - 1);
    const int flo = 3 * ilo;
    const int fhi = 3 * ihi + 3;

    // ---- window addressing: outputs e0..e0+11 need elements [A, A+20] ----
    const int e0 = c * 12;
    const int A  = e0 - 6 - 3 * dfl;
    const int p  = A & 3;                 // wave-uniform (depends only on dfl)
    const int a0 = A - p;                 // float4-aligned window start (may be <0)

    // ---- load 24-float window, index-clamped (OOB taps are masked below) ----
    const float4* src4 = (const float4*)hist + (size_t)b * ROWF4;
    float w[24];
    #pragma unroll
    for (int q = 0; q < 6; ++q) {
        int idx = (a0 >> 2) + q;
        idx = min(max(idx, 0), ROWF4 - 1);
        const float4 v = src4[idx];
        w[4*q+0] = v.x; w[4*q+1] = v.y; w[4*q+2] = v.z; w[4*q+3] = v.w;
    }

    // ---- injection into first 5 bins (elements f in [0,15)); few lanes/wave ----
    if (a0 < 15) {
        const float am = fminf(fmaxf(*p_amount, 0.0f), 1.0f);
        const float sp = fminf(fmaxf(*p_spread, 0.0f), 1.0f);
        const float tight = 1.0f - sp;
        const float aw0 = am * fmaf(0.4f, tight, 0.5f);
        const float aw1 = am * fmaf(0.2f, sp, 0.05f);
        const float aw2 = am * (0.12f * sp);
        const float aw3 = am * (0.06f * sp);
        const float aw4 = am * (0.02f * sp);
        const float c0 = color[3*b+0];
        const float c1 = color[3*b+1];
        const float c2 = color[3*b+2];
        #pragma unroll
        for (int u = 0; u < 24; ++u) {
            const int f = a0 + u;
            if ((unsigned)f < 15u) {
                const int bin = f / 3;
                const int ch  = f - 3 * bin;
                const float cv = (ch == 0) ? c0 : (ch == 1) ? c1 : c2;
                const float av = (bin == 0) ? aw0 : (bin == 1) ? aw1 :
                                 (bin == 2) ? aw2 : (bin == 3) ? aw3 : aw4;
                w[u] += cv * av;
            }
        }
    }

    // ---- mask (valid source range) + clamp01, one pass over the window ----
    #pragma unroll
    for (int u = 0; u < 24; ++u) {
        const int f = a0 + u;
        const bool m = (f >= flo) && (f < fhi);
        w[u] = m ? clamp01(w[u]) : 0.0f;
    }

    // ---- 4-tap stencil + fade + float4 stores ----
    float4* dst = (float4*)(out + (size_t)b * ROWELEMS + e0);
    const bool dofade = (c >= TASKS_PER_ROW - 2);   // bins >= 152
    const int j0 = 4 * c;
    switch (p) {
        case 0:  stencil_store<0>(w, u1, u2, u3, u4, dst, dofade, j0); break;
        case 1:  stencil_store<1>(w, u1, u2, u3, u4, dst, dofade, j0); break;
        case 2:  stencil_store<2>(w, u1, u2, u3, u4, dst, dofade, j0); break;
        default: stencil_store<3>(w, u1, u2, u3, u4, dst, dofade, j0); break;
    }
}

extern "C" void kernel_launch(void* const* d_in, const int* in_sizes, int n_in,
                              void* d_out, int out_size, void* d_ws, size_t ws_size,
                              hipStream_t stream) {
    const float* hist      = (const float*)d_in[0];
    const float* color     = (const float*)d_in[1];
    const float* p_offset  = (const float*)d_in[2];
    const float* p_persist = (const float*)d_in[3];
    const float* p_diff    = (const float*)d_in[4];
    const float* p_dt      = (const float*)d_in[5];
    const float* p_amount  = (const float*)d_in[6];
    const float* p_spread  = (const float*)d_in[7];
    float* outp = (float*)d_out;

    beat_kernel<<<dim3(NBLOCKS), dim3(NTHREADS), 0, stream>>>(
        hist, color, p_offset, p_persist, p_diff, p_dt, p_amount, p_spread, outp);
}